// Round 1
// baseline (194.188 us; speedup 1.0000x reference)
//
#include <hip/hip_runtime.h>

// Problem constants (from reference): H=8, D=128 -> 1024 floats per (token,allheads) row
// PAGE=16 slots per page; cache layout [npages][2][PAGE][H][D] fp32.
#define PAGE_SZ 16
#define ROW_FLOATS 1024          // H*D
#define ROW_F4 256               // ROW_FLOATS/4
#define ROWS_PER_PAGE 32         // 2*PAGE_SZ
#define ELEMS_PER_PAGE 32768     // ROWS_PER_PAGE*ROW_FLOATS

// map[p] = (-1, _)        : page untouched by append
//          ( 1, t_base)   : page fully covered; slot s sources token t_base+s
//          ( 2, (b<<20)|j): page partially covered; recompute per-slot
__global__ void init_map_kernel(int2* __restrict__ map, int npages) {
    int i = blockIdx.x * blockDim.x + threadIdx.x;
    if (i < npages) map[i] = make_int2(-1, 0);
}

__global__ void fill_map_kernel(const int* __restrict__ append_indptr,
                                const int* __restrict__ page_indices,
                                const int* __restrict__ page_indptr,
                                const int* __restrict__ lastlen,
                                int2* __restrict__ map,
                                int B, int max_entries) {
    int idx = blockIdx.x * blockDim.x + threadIdx.x;
    if (idx >= max_entries) return;
    if (idx >= page_indptr[B]) return;        // beyond used page entries
    // find request b with page_indptr[b] <= idx < page_indptr[b+1]
    int b = 0;
    while (page_indptr[b + 1] <= idx) b++;
    int j         = idx - page_indptr[b];
    int num_pages = page_indptr[b + 1] - page_indptr[b];
    int num_new   = append_indptr[b + 1] - append_indptr[b];
    int seq_len   = (num_pages - 1) * PAGE_SZ + lastlen[b];
    int start     = seq_len - num_new;        // first appended logical position
    int pos0      = j * PAGE_SZ;
    int lo = pos0 > start ? pos0 : start;
    int hi = (pos0 + PAGE_SZ) < seq_len ? (pos0 + PAGE_SZ) : seq_len;
    if (lo >= hi) return;                     // no new tokens land in this page
    int p = page_indices[idx];
    if (pos0 >= start && pos0 + PAGE_SZ <= seq_len) {
        map[p] = make_int2(1, append_indptr[b] + pos0 - start);   // full page
    } else {
        map[p] = make_int2(2, (b << 20) | j);                     // partial page
    }
}

// One block per (page, kv, slot) row: 256 threads x float4 = 4 KiB, coalesced.
__global__ void gather_kernel(const float4* __restrict__ k,
                              const float4* __restrict__ v,
                              const float4* __restrict__ cache_in,
                              const int* __restrict__ append_indptr,
                              const int* __restrict__ page_indptr,
                              const int* __restrict__ lastlen,
                              const int2* __restrict__ map,
                              float4* __restrict__ out) {
    int bid   = blockIdx.x;
    int page  = bid >> 5;          // /ROWS_PER_PAGE
    int row   = bid & 31;
    int kvsel = row >> 4;
    int slot  = row & 15;
    int tid   = threadIdx.x;       // float4 index within row
    long e4   = (long)bid * ROW_F4 + tid;

    int2 m = map[page];
    float4 val;
    if (m.x == 1) {
        long t = (long)(m.y + slot);
        const float4* src = kvsel ? v : k;
        val = src[t * ROW_F4 + tid];
    } else if (m.x < 0) {
        val = cache_in[e4];
    } else {
        int b = m.y >> 20, j = m.y & 0xFFFFF;
        int num_pages = page_indptr[b + 1] - page_indptr[b];
        int num_new   = append_indptr[b + 1] - append_indptr[b];
        int seq_len   = (num_pages - 1) * PAGE_SZ + lastlen[b];
        int start     = seq_len - num_new;
        int pos       = j * PAGE_SZ + slot;
        if (pos >= start && pos < seq_len) {
            long t = (long)(append_indptr[b] + pos - start);
            const float4* src = kvsel ? v : k;
            val = src[t * ROW_F4 + tid];
        } else {
            val = cache_in[e4];
        }
    }
    out[e4] = val;
}

extern "C" void kernel_launch(void* const* d_in, const int* in_sizes, int n_in,
                              void* d_out, int out_size, void* d_ws, size_t ws_size,
                              hipStream_t stream) {
    const float4* k        = (const float4*)d_in[0];
    const float4* v        = (const float4*)d_in[1];
    const float4* cache_in = (const float4*)d_in[2];
    const int* append_indptr = (const int*)d_in[3];
    const int* page_indices  = (const int*)d_in[4];
    const int* page_indptr   = (const int*)d_in[5];
    const int* lastlen       = (const int*)d_in[6];
    // d_in[7] is page_size (=16), hard-coded as PAGE_SZ per reference constants.

    int B           = in_sizes[3] - 1;         // 8
    int max_entries = in_sizes[4];             // 2048
    int npages      = (int)((long)out_size / ELEMS_PER_PAGE);  // 4096

    int2* map = (int2*)d_ws;                   // npages * 8 bytes = 32 KiB

    init_map_kernel<<<(npages + 255) / 256, 256, 0, stream>>>(map, npages);
    fill_map_kernel<<<(max_entries + 255) / 256, 256, 0, stream>>>(
        append_indptr, page_indices, page_indptr, lastlen, map, B, max_entries);
    gather_kernel<<<npages * ROWS_PER_PAGE, 256, 0, stream>>>(
        k, v, cache_in, append_indptr, page_indptr, lastlen, map,
        (float4*)d_out);
}